// Round 5
// baseline (769.670 us; speedup 1.0000x reference)
//
#include <hip/hip_runtime.h>

typedef __bf16 bf16_t;
typedef bf16_t bf16x8 __attribute__((ext_vector_type(8)));
typedef float f32x4 __attribute__((ext_vector_type(4)));
typedef unsigned short u16x8_t __attribute__((ext_vector_type(8)));
typedef unsigned int u32x4_t __attribute__((ext_vector_type(4)));

#define HD 64
#define TOTTOK 49152

__device__ __forceinline__ unsigned short f2b(float f) {
    bf16_t h = (bf16_t)f;
    return __builtin_bit_cast(unsigned short, h);
}
__device__ __forceinline__ bf16x8 asbf(u16x8_t u) { return __builtin_bit_cast(bf16x8, u); }
__device__ __forceinline__ bf16x8 asbf4(u32x4_t u) { return __builtin_bit_cast(bf16x8, u); }

__global__ __launch_bounds__(256, 3)
void flash_attn_kernel(const float* __restrict__ Q, const float* __restrict__ K,
                       const float* __restrict__ V, float* __restrict__ O)
{
    // K fragment-major: chunk ck=kt*2+c (512 shorts each), lane l holds
    // K[kt*16+(l&15)][c*32+(l>>4)*8 ..+8). Writes are flat lane-linear b128.
    __shared__ unsigned short Kf[2][4096];
    // V^T: addr(key,d) = (key>>2)*520 + d*8 + (key&3)*2  (520B pad: writes and
    // b64 reads both land at the exact 4-phase LDS minimum, zero conflict tax)
    __shared__ unsigned short Vf[2][4160];

    const int bid = blockIdx.x;
    int Slen, bl2, off, qtl2, base;
    if (bid < 512)       { Slen = 2048; bl2 = 3; off = 32768; qtl2 = 3; base = 0;    }
    else if (bid < 1024) { Slen = 1024; bl2 = 4; off = 16384; qtl2 = 2; base = 512;  }
    else                 { Slen = 512;  bl2 = 5; off = 0;     qtl2 = 1; base = 1024; }
    const int l    = bid - base;
    const int xcd  = l & 7;
    const int slot = l >> 3;
    const int p    = xcd + ((slot >> qtl2) << 3);
    const int qt   = slot & ((1 << qtl2) - 1);
    const int hh   = p >> bl2;
    const int sj   = p & ((1 << bl2) - 1);

    const size_t seqbase = ((size_t)hh * TOTTOK + (size_t)off + (size_t)sj * Slen) * HD;
    const float* Qb = Q + seqbase + (size_t)(qt * 256) * HD;
    const float* Kb = K + seqbase;
    const float* Vb = V + seqbase;
    float*       Ob = O + seqbase + (size_t)(qt * 256) * HD;

    const int tid  = threadIdx.x;
    const int wave = tid >> 6;
    const int lane = tid & 63;
    const int lg   = lane >> 4;
    const int li   = lane & 15;
    const bool lam = (lg & 1) != 0;

    const float SC = 0.125f * 1.4426950408889634f;  // 1/sqrt(64) * log2(e)

    // ---- Q fragments (B-operand: n=li=query, k=c*32+lg*8+i), 64 q/wave ----
    bf16x8 qh[4][2];
#pragma unroll
    for (int st = 0; st < 4; ++st)
#pragma unroll
      for (int c = 0; c < 2; ++c) {
        const float* src = Qb + (size_t)(wave*64 + st*16 + li) * HD + c*32 + lg*8;
        float4 a = *(const float4*)src;
        float4 b = *(const float4*)(src + 4);
        float f[8] = {a.x,a.y,a.z,a.w,b.x,b.y,b.z,b.w};
        bf16x8 hi;
#pragma unroll
        for (int i = 0; i < 8; ++i) hi[i] = (bf16_t)(f[i] * SC);
        qh[st][c] = hi;
      }

    f32x4 oacc[4][4];     // O^T[d=16t+4lg+rr][q=li], stripe st
    f32x4 lacc[4];        // l[q=li] via ones-MFMA (bf16-P sum -> error cancels)
    float mrow[4];
#pragma unroll
    for (int st = 0; st < 4; ++st) {
      mrow[st] = -1e30f;
      lacc[st] = (f32x4){0.f,0.f,0.f,0.f};
#pragma unroll
      for (int t = 0; t < 4; ++t) oacc[st][t] = (f32x4){0.f,0.f,0.f,0.f};
    }

    u16x8_t onesu;
#pragma unroll
    for (int i = 0; i < 8; ++i) onesu[i] = 0x3F80;
    const bf16x8 ones = asbf(onesu);

    // ---- staging maps ----
    // K: thread t sources K[krow(+32)][kd0..kd0+8) so that its LDS write is
    // flat byte t*16 (half W=0) / 4096+t*16 (W=1). Per-row global access is
    // 4 threads x 32B contiguous = fully coalesced.
    const int krow = ((tid >> 7) & 1) * 16 + (tid & 15);
    const int kd0  = ((tid >> 6) & 1) * 32 + ((tid >> 4) & 3) * 8;
    // V: 4x4 fp32 block, in-thread transpose, 4x ushort4 writes
    const int vkg  = (tid & 15) * 4;
    const int vdc  = (tid >> 4) * 4;

    float4 kr0, kr1, kr2, kr3, vr[4];
    auto LOADT = [&](int it) {
      const float* Ksrc = Kb + (size_t)(it * 64) * HD;
      const float* Vsrc = Vb + (size_t)(it * 64) * HD;
      kr0 = *(const float4*)(Ksrc + (size_t)krow * HD + kd0);
      kr1 = *(const float4*)(Ksrc + (size_t)krow * HD + kd0 + 4);
      kr2 = *(const float4*)(Ksrc + (size_t)(krow + 32) * HD + kd0);
      kr3 = *(const float4*)(Ksrc + (size_t)(krow + 32) * HD + kd0 + 4);
#pragma unroll
      for (int i = 0; i < 4; ++i)
        vr[i] = *(const float4*)(Vsrc + (size_t)(vkg + i) * HD + vdc);
    };
    auto STORET = [&](int buf) {
      unsigned short* kdst = &Kf[buf][0];
      u16x8_t a;
      a[0]=f2b(kr0.x); a[1]=f2b(kr0.y); a[2]=f2b(kr0.z); a[3]=f2b(kr0.w);
      a[4]=f2b(kr1.x); a[5]=f2b(kr1.y); a[6]=f2b(kr1.z); a[7]=f2b(kr1.w);
      *(u16x8_t*)(kdst + tid*8) = a;
      a[0]=f2b(kr2.x); a[1]=f2b(kr2.y); a[2]=f2b(kr2.z); a[3]=f2b(kr2.w);
      a[4]=f2b(kr3.x); a[5]=f2b(kr3.y); a[6]=f2b(kr3.z); a[7]=f2b(kr3.w);
      *(u16x8_t*)(kdst + 2048 + tid*8) = a;

      float vm[4][4];
#pragma unroll
      for (int i = 0; i < 4; ++i) {
        vm[i][0] = vr[i].x; vm[i][1] = vr[i].y; vm[i][2] = vr[i].z; vm[i][3] = vr[i].w;
      }
      char* vdst = (char*)&Vf[buf][0] + (vkg >> 2) * 520;
#pragma unroll
      for (int j = 0; j < 4; ++j) {
        ushort4 u;
        u.x = f2b(vm[0][j]); u.y = f2b(vm[1][j]); u.z = f2b(vm[2][j]); u.w = f2b(vm[3][j]);
        *(ushort4*)(vdst + (vdc + j) * 8) = u;
      }
    };

    const int niter = Slen >> 6;
    LOADT(0);
    STORET(0);
    __syncthreads();

    for (int it = 0; it < niter; ++it) {
      const int cur = it & 1;
      const bool more = (it + 1 < niter);
      if (more) LOADT(it + 1);   // T14: issue early, LDS-write after compute

      // K fragments: lane-linear b128, held across stripes
      bf16x8 kf[4][2];
#pragma unroll
      for (int kt = 0; kt < 4; ++kt)
#pragma unroll
        for (int c = 0; c < 2; ++c)
          kf[kt][c] = asbf(*(const u16x8_t*)&Kf[cur][(kt*2 + c)*512 + lane*8]);

      u32x4_t pb[4][2];
#pragma unroll
      for (int st = 0; st < 4; ++st) {
        f32x4 s[4];
        __builtin_amdgcn_s_setprio(1);
#pragma unroll
        for (int kt = 0; kt < 4; ++kt) {
          f32x4 z = (f32x4){0.f,0.f,0.f,0.f};
          z = __builtin_amdgcn_mfma_f32_16x16x32_bf16(kf[kt][0], qh[st][0], z, 0, 0, 0);
          z = __builtin_amdgcn_mfma_f32_16x16x32_bf16(kf[kt][1], qh[st][1], z, 0, 0, 0);
          s[kt] = z;
        }
        __builtin_amdgcn_s_setprio(0);

        // ---- defer-max online softmax (T13)
        float p01 = fmaxf(fmaxf(s[0][0], s[0][1]), fmaxf(s[0][2], s[0][3]));
        float p23 = fmaxf(fmaxf(s[1][0], s[1][1]), fmaxf(s[1][2], s[1][3]));
        float p45 = fmaxf(fmaxf(s[2][0], s[2][1]), fmaxf(s[2][2], s[2][3]));
        float p67 = fmaxf(fmaxf(s[3][0], s[3][1]), fmaxf(s[3][2], s[3][3]));
        float pmax = fmaxf(fmaxf(p01, p23), fmaxf(p45, p67));
        if (!__all(pmax <= mrow[st] + 8.0f)) {
          float mx = pmax;
          mx = fmaxf(mx, __shfl_xor(mx, 16));
          mx = fmaxf(mx, __shfl_xor(mx, 32));
          float mnew = fmaxf(mrow[st], mx);
          float corr = __builtin_amdgcn_exp2f(mrow[st] - mnew);
          mrow[st] = mnew;
          lacc[st] *= corr;
#pragma unroll
          for (int t = 0; t < 4; ++t) oacc[st][t] *= corr;
        }
        const float m = mrow[st];
        unsigned int W[4][2];
#pragma unroll
        for (int kt = 0; kt < 4; ++kt) {
#pragma unroll
          for (int jw = 0; jw < 2; ++jw) {
            float e0 = __builtin_amdgcn_exp2f(s[kt][2*jw]   - m);
            float e1 = __builtin_amdgcn_exp2f(s[kt][2*jw+1] - m);
            W[kt][jw] = (unsigned int)f2b(e0) | ((unsigned int)f2b(e1) << 16);
          }
        }
        // ---- in-register P -> B-fragment exchange
#pragma unroll
        for (int c = 0; c < 2; ++c) {
          unsigned int a0 = W[2*c][0], b0 = W[2*c+1][0];
          unsigned int a1 = W[2*c][1], b1 = W[2*c+1][1];
          asm("v_permlane32_swap_b32 %0, %1" : "+v"(a0), "+v"(b0));
          asm("v_permlane32_swap_b32 %0, %1" : "+v"(a1), "+v"(b1));
          unsigned int q0 = lam ? a0 : b0;
          unsigned int q1 = lam ? a1 : b1;
          unsigned int s0 = __builtin_amdgcn_ds_swizzle((int)q0, 0x401F); // xor16
          unsigned int s1 = __builtin_amdgcn_ds_swizzle((int)q1, 0x401F);
          u32x4_t pw;
          pw[0] = lam ? s0 : a0;
          pw[1] = lam ? s1 : a1;
          pw[2] = lam ? b0 : s0;
          pw[3] = lam ? b1 : s1;
          pb[st][c] = pw;
        }
      }

      // ---- PV: O^T += V^T . P^T ; l += ones . P^T (MFMA pipe has headroom)
      const char* vrb = (const char*)&Vf[cur][0] + (lane >> 4) * 1040 + (lane & 15) * 8;
      __builtin_amdgcn_s_setprio(1);
#pragma unroll
      for (int c = 0; c < 2; ++c) {
        bf16x8 pbf[4];
#pragma unroll
        for (int st = 0; st < 4; ++st) {
          pbf[st] = asbf4(pb[st][c]);
          lacc[st] = __builtin_amdgcn_mfma_f32_16x16x32_bf16(ones, pbf[st], lacc[st], 0, 0, 0);
        }
#pragma unroll
        for (int t = 0; t < 4; ++t) {
          ushort4 lo4 = *(const ushort4*)(vrb + (c*8 + 0)*520 + t*128);
          ushort4 hi4 = *(const ushort4*)(vrb + (c*8 + 1)*520 + t*128);
          u16x8_t vv;
          vv[0]=lo4.x; vv[1]=lo4.y; vv[2]=lo4.z; vv[3]=lo4.w;
          vv[4]=hi4.x; vv[5]=hi4.y; vv[6]=hi4.z; vv[7]=hi4.w;
          bf16x8 vbf = asbf(vv);
          oacc[0][t] = __builtin_amdgcn_mfma_f32_16x16x32_bf16(vbf, pbf[0], oacc[0][t], 0, 0, 0);
          oacc[1][t] = __builtin_amdgcn_mfma_f32_16x16x32_bf16(vbf, pbf[1], oacc[1][t], 0, 0, 0);
          oacc[2][t] = __builtin_amdgcn_mfma_f32_16x16x32_bf16(vbf, pbf[2], oacc[2][t], 0, 0, 0);
          oacc[3][t] = __builtin_amdgcn_mfma_f32_16x16x32_bf16(vbf, pbf[3], oacc[3][t], 0, 0, 0);
        }
      }
      __builtin_amdgcn_s_setprio(0);

      if (more) {
        STORET(cur ^ 1);
        __syncthreads();
      }
    }

    // ---- epilogue
#pragma unroll
    for (int st = 0; st < 4; ++st) {
      float inv = 1.0f / lacc[st][0];
      float* dst = Ob + (size_t)(wave*64 + st*16 + li) * HD + lg*4;
#pragma unroll
      for (int t = 0; t < 4; ++t) {
        float4 o4;
        o4.x = oacc[st][t][0] * inv;
        o4.y = oacc[st][t][1] * inv;
        o4.z = oacc[st][t][2] * inv;
        o4.w = oacc[st][t][3] * inv;
        *(float4*)(dst + t*16) = o4;
      }
    }
}

extern "C" void kernel_launch(void* const* d_in, const int* in_sizes, int n_in,
                              void* d_out, int out_size, void* d_ws, size_t ws_size,
                              hipStream_t stream) {
    (void)in_sizes; (void)n_in; (void)out_size; (void)d_ws; (void)ws_size;
    const float* Q = (const float*)d_in[0];
    const float* K = (const float*)d_in[1];
    const float* V = (const float*)d_in[2];
    float* O = (float*)d_out;
    flash_attn_kernel<<<dim3(1536), dim3(256), 0, stream>>>(Q, K, V, O);
}

// Round 6
// 228.391 us; speedup vs baseline: 3.3700x; 3.3700x over previous
//
#include <hip/hip_runtime.h>

typedef __bf16 bf16_t;
typedef bf16_t bf16x8 __attribute__((ext_vector_type(8)));
typedef float f32x4 __attribute__((ext_vector_type(4)));
typedef unsigned short u16x8_t __attribute__((ext_vector_type(8)));
typedef unsigned int u32x4_t __attribute__((ext_vector_type(4)));

#define HD 64
#define TOTTOK 49152

__device__ __forceinline__ unsigned short f2b(float f) {
    bf16_t h = (bf16_t)f;
    return __builtin_bit_cast(unsigned short, h);
}
__device__ __forceinline__ bf16x8 asbf(u16x8_t u) { return __builtin_bit_cast(bf16x8, u); }
__device__ __forceinline__ bf16x8 asbf4(u32x4_t u) { return __builtin_bit_cast(bf16x8, u); }

__global__ __launch_bounds__(256, 2)   // 2 blocks/CU: 256-VGPR budget, NO spill
void flash_attn_kernel(const float* __restrict__ Q, const float* __restrict__ K,
                       const float* __restrict__ V, float* __restrict__ O)
{
    // K fragment-major: chunk ck=kt*2+c (512 shorts each), lane l holds
    // K[kt*16+(l&15)][c*32+(l>>4)*8 ..+8). Writes are flat lane-linear b128.
    __shared__ unsigned short Kf[2][4096];
    // V^T: addr(key,d) = (key>>2)*520 + d*8 + (key&3)*2  (520B pad: writes and
    // b64 reads both land at the exact 4-phase LDS minimum, zero conflict tax)
    __shared__ unsigned short Vf[2][4160];

    const int bid = blockIdx.x;
    int Slen, bl2, off, qtl2, base;
    if (bid < 512)       { Slen = 2048; bl2 = 3; off = 32768; qtl2 = 3; base = 0;    }
    else if (bid < 1024) { Slen = 1024; bl2 = 4; off = 16384; qtl2 = 2; base = 512;  }
    else                 { Slen = 512;  bl2 = 5; off = 0;     qtl2 = 1; base = 1024; }
    const int l    = bid - base;
    const int xcd  = l & 7;
    const int slot = l >> 3;
    const int p    = xcd + ((slot >> qtl2) << 3);
    const int qt   = slot & ((1 << qtl2) - 1);
    const int hh   = p >> bl2;
    const int sj   = p & ((1 << bl2) - 1);

    const size_t seqbase = ((size_t)hh * TOTTOK + (size_t)off + (size_t)sj * Slen) * HD;
    const float* Qb = Q + seqbase + (size_t)(qt * 256) * HD;
    const float* Kb = K + seqbase;
    const float* Vb = V + seqbase;
    float*       Ob = O + seqbase + (size_t)(qt * 256) * HD;

    const int tid  = threadIdx.x;
    const int wave = tid >> 6;
    const int lane = tid & 63;
    const int lg   = lane >> 4;
    const int li   = lane & 15;
    const bool lam = (lg & 1) != 0;

    const float SC = 0.125f * 1.4426950408889634f;  // 1/sqrt(64) * log2(e)

    // ---- Q fragments (B-operand: n=li=query, k=c*32+lg*8+i), 64 q/wave ----
    bf16x8 qh[4][2];
#pragma unroll
    for (int st = 0; st < 4; ++st)
#pragma unroll
      for (int c = 0; c < 2; ++c) {
        const float* src = Qb + (size_t)(wave*64 + st*16 + li) * HD + c*32 + lg*8;
        float4 a = *(const float4*)src;
        float4 b = *(const float4*)(src + 4);
        float f[8] = {a.x,a.y,a.z,a.w,b.x,b.y,b.z,b.w};
        bf16x8 hi;
#pragma unroll
        for (int i = 0; i < 8; ++i) hi[i] = (bf16_t)(f[i] * SC);
        qh[st][c] = hi;
      }

    f32x4 oacc[4][4];     // O^T[d=16t+4lg+rr][q=li], stripe st
    f32x4 lacc[4];        // l[q=li] via ones-MFMA (bf16-P sum -> error cancels)
    float mrow[4];
#pragma unroll
    for (int st = 0; st < 4; ++st) {
      mrow[st] = -1e30f;
      lacc[st] = (f32x4){0.f,0.f,0.f,0.f};
#pragma unroll
      for (int t = 0; t < 4; ++t) oacc[st][t] = (f32x4){0.f,0.f,0.f,0.f};
    }

    u16x8_t onesu;
#pragma unroll
    for (int i = 0; i < 8; ++i) onesu[i] = 0x3F80;
    const bf16x8 ones = asbf(onesu);

    // ---- staging maps ----
    // K: thread t sources K[krow(+32)][kd0..kd0+8) so that its LDS write is
    // flat byte t*16 (half W=0) / 4096+t*16 (W=1). Per-row global access is
    // 4 threads x 32B contiguous = fully coalesced.
    const int krow = ((tid >> 7) & 1) * 16 + (tid & 15);
    const int kd0  = ((tid >> 6) & 1) * 32 + ((tid >> 4) & 3) * 8;
    // V: 4x4 fp32 block, in-thread transpose, 4x ushort4 writes
    const int vkg  = (tid & 15) * 4;
    const int vdc  = (tid >> 4) * 4;

    float4 kr0, kr1, kr2, kr3, vr[4];
    auto LOADT = [&](int it) {
      const float* Ksrc = Kb + (size_t)(it * 64) * HD;
      const float* Vsrc = Vb + (size_t)(it * 64) * HD;
      kr0 = *(const float4*)(Ksrc + (size_t)krow * HD + kd0);
      kr1 = *(const float4*)(Ksrc + (size_t)krow * HD + kd0 + 4);
      kr2 = *(const float4*)(Ksrc + (size_t)(krow + 32) * HD + kd0);
      kr3 = *(const float4*)(Ksrc + (size_t)(krow + 32) * HD + kd0 + 4);
#pragma unroll
      for (int i = 0; i < 4; ++i)
        vr[i] = *(const float4*)(Vsrc + (size_t)(vkg + i) * HD + vdc);
    };
    auto STORET = [&](int buf) {
      unsigned short* kdst = &Kf[buf][0];
      u16x8_t a;
      a[0]=f2b(kr0.x); a[1]=f2b(kr0.y); a[2]=f2b(kr0.z); a[3]=f2b(kr0.w);
      a[4]=f2b(kr1.x); a[5]=f2b(kr1.y); a[6]=f2b(kr1.z); a[7]=f2b(kr1.w);
      *(u16x8_t*)(kdst + tid*8) = a;
      a[0]=f2b(kr2.x); a[1]=f2b(kr2.y); a[2]=f2b(kr2.z); a[3]=f2b(kr2.w);
      a[4]=f2b(kr3.x); a[5]=f2b(kr3.y); a[6]=f2b(kr3.z); a[7]=f2b(kr3.w);
      *(u16x8_t*)(kdst + 2048 + tid*8) = a;

      float vm[4][4];
#pragma unroll
      for (int i = 0; i < 4; ++i) {
        vm[i][0] = vr[i].x; vm[i][1] = vr[i].y; vm[i][2] = vr[i].z; vm[i][3] = vr[i].w;
      }
      char* vdst = (char*)&Vf[buf][0] + (vkg >> 2) * 520;
#pragma unroll
      for (int j = 0; j < 4; ++j) {
        ushort4 u;
        u.x = f2b(vm[0][j]); u.y = f2b(vm[1][j]); u.z = f2b(vm[2][j]); u.w = f2b(vm[3][j]);
        *(ushort4*)(vdst + (vdc + j) * 8) = u;
      }
    };

    const int niter = Slen >> 6;
    LOADT(0);
    STORET(0);
    __syncthreads();

    for (int it = 0; it < niter; ++it) {
      const int cur = it & 1;
      const bool more = (it + 1 < niter);
      if (more) LOADT(it + 1);   // T14: issue early, LDS-write after compute

      // K fragments: lane-linear b128, held across stripes
      bf16x8 kf[4][2];
#pragma unroll
      for (int kt = 0; kt < 4; ++kt)
#pragma unroll
        for (int c = 0; c < 2; ++c)
          kf[kt][c] = asbf(*(const u16x8_t*)&Kf[cur][(kt*2 + c)*512 + lane*8]);

      u32x4_t pb[4][2];
#pragma unroll
      for (int st = 0; st < 4; ++st) {
        f32x4 s[4];
        __builtin_amdgcn_s_setprio(1);
#pragma unroll
        for (int kt = 0; kt < 4; ++kt) {
          f32x4 z = (f32x4){0.f,0.f,0.f,0.f};
          z = __builtin_amdgcn_mfma_f32_16x16x32_bf16(kf[kt][0], qh[st][0], z, 0, 0, 0);
          z = __builtin_amdgcn_mfma_f32_16x16x32_bf16(kf[kt][1], qh[st][1], z, 0, 0, 0);
          s[kt] = z;
        }
        __builtin_amdgcn_s_setprio(0);

        // ---- defer-max online softmax (T13)
        float p01 = fmaxf(fmaxf(s[0][0], s[0][1]), fmaxf(s[0][2], s[0][3]));
        float p23 = fmaxf(fmaxf(s[1][0], s[1][1]), fmaxf(s[1][2], s[1][3]));
        float p45 = fmaxf(fmaxf(s[2][0], s[2][1]), fmaxf(s[2][2], s[2][3]));
        float p67 = fmaxf(fmaxf(s[3][0], s[3][1]), fmaxf(s[3][2], s[3][3]));
        float pmax = fmaxf(fmaxf(p01, p23), fmaxf(p45, p67));
        if (!__all(pmax <= mrow[st] + 8.0f)) {
          float mx = pmax;
          mx = fmaxf(mx, __shfl_xor(mx, 16));
          mx = fmaxf(mx, __shfl_xor(mx, 32));
          float mnew = fmaxf(mrow[st], mx);
          float corr = __builtin_amdgcn_exp2f(mrow[st] - mnew);
          mrow[st] = mnew;
          lacc[st] *= corr;
#pragma unroll
          for (int t = 0; t < 4; ++t) oacc[st][t] *= corr;
        }
        const float m = mrow[st];
        unsigned int W[4][2];
#pragma unroll
        for (int kt = 0; kt < 4; ++kt) {
#pragma unroll
          for (int jw = 0; jw < 2; ++jw) {
            float e0 = __builtin_amdgcn_exp2f(s[kt][2*jw]   - m);
            float e1 = __builtin_amdgcn_exp2f(s[kt][2*jw+1] - m);
            W[kt][jw] = (unsigned int)f2b(e0) | ((unsigned int)f2b(e1) << 16);
          }
        }
        // ---- in-register P -> B-fragment exchange
#pragma unroll
        for (int c = 0; c < 2; ++c) {
          unsigned int a0 = W[2*c][0], b0 = W[2*c+1][0];
          unsigned int a1 = W[2*c][1], b1 = W[2*c+1][1];
          asm("v_permlane32_swap_b32 %0, %1" : "+v"(a0), "+v"(b0));
          asm("v_permlane32_swap_b32 %0, %1" : "+v"(a1), "+v"(b1));
          unsigned int q0 = lam ? a0 : b0;
          unsigned int q1 = lam ? a1 : b1;
          unsigned int s0 = __builtin_amdgcn_ds_swizzle((int)q0, 0x401F); // xor16
          unsigned int s1 = __builtin_amdgcn_ds_swizzle((int)q1, 0x401F);
          u32x4_t pw;
          pw[0] = lam ? s0 : a0;
          pw[1] = lam ? s1 : a1;
          pw[2] = lam ? b0 : s0;
          pw[3] = lam ? b1 : s1;
          pb[st][c] = pw;
        }
      }

      // ---- PV: O^T += V^T . P^T ; l += ones . P^T (MFMA pipe has headroom)
      const char* vrb = (const char*)&Vf[cur][0] + (lane >> 4) * 1040 + (lane & 15) * 8;
      __builtin_amdgcn_s_setprio(1);
#pragma unroll
      for (int c = 0; c < 2; ++c) {
        bf16x8 pbf[4];
#pragma unroll
        for (int st = 0; st < 4; ++st) {
          pbf[st] = asbf4(pb[st][c]);
          lacc[st] = __builtin_amdgcn_mfma_f32_16x16x32_bf16(ones, pbf[st], lacc[st], 0, 0, 0);
        }
#pragma unroll
        for (int t = 0; t < 4; ++t) {
          ushort4 lo4 = *(const ushort4*)(vrb + (c*8 + 0)*520 + t*128);
          ushort4 hi4 = *(const ushort4*)(vrb + (c*8 + 1)*520 + t*128);
          u16x8_t vv;
          vv[0]=lo4.x; vv[1]=lo4.y; vv[2]=lo4.z; vv[3]=lo4.w;
          vv[4]=hi4.x; vv[5]=hi4.y; vv[6]=hi4.z; vv[7]=hi4.w;
          bf16x8 vbf = asbf(vv);
          oacc[0][t] = __builtin_amdgcn_mfma_f32_16x16x32_bf16(vbf, pbf[0], oacc[0][t], 0, 0, 0);
          oacc[1][t] = __builtin_amdgcn_mfma_f32_16x16x32_bf16(vbf, pbf[1], oacc[1][t], 0, 0, 0);
          oacc[2][t] = __builtin_amdgcn_mfma_f32_16x16x32_bf16(vbf, pbf[2], oacc[2][t], 0, 0, 0);
          oacc[3][t] = __builtin_amdgcn_mfma_f32_16x16x32_bf16(vbf, pbf[3], oacc[3][t], 0, 0, 0);
        }
      }
      __builtin_amdgcn_s_setprio(0);

      if (more) {
        STORET(cur ^ 1);
        __syncthreads();
      }
    }

    // ---- epilogue
#pragma unroll
    for (int st = 0; st < 4; ++st) {
      float inv = 1.0f / lacc[st][0];
      float* dst = Ob + (size_t)(wave*64 + st*16 + li) * HD + lg*4;
#pragma unroll
      for (int t = 0; t < 4; ++t) {
        float4 o4;
        o4.x = oacc[st][t][0] * inv;
        o4.y = oacc[st][t][1] * inv;
        o4.z = oacc[st][t][2] * inv;
        o4.w = oacc[st][t][3] * inv;
        *(float4*)(dst + t*16) = o4;
      }
    }
}

extern "C" void kernel_launch(void* const* d_in, const int* in_sizes, int n_in,
                              void* d_out, int out_size, void* d_ws, size_t ws_size,
                              hipStream_t stream) {
    (void)in_sizes; (void)n_in; (void)out_size; (void)d_ws; (void)ws_size;
    const float* Q = (const float*)d_in[0];
    const float* K = (const float*)d_in[1];
    const float* V = (const float*)d_in[2];
    float* O = (float*)d_out;
    flash_attn_kernel<<<dim3(1536), dim3(256), 0, stream>>>(Q, K, V, O);
}